// Round 5
// baseline (180.820 us; speedup 1.0000x reference)
//
#include <hip/hip_runtime.h>
#include <hip/hip_bf16.h>

// SparseConv3D v5: barrier-free tap loop.
// Per 128-row tile: build tbl[tap][m] = in_row or -1 (one barrier), then 27 taps
// with register double-buffered A (gather) + B (L2-hot bf16 weights), zero
// __syncthreads in the loop -> per-block critical path ~ MFMA issue, not latency.
// Wave partition: w>>1 = row half (64 rows, 4 mt), w&1 = cout half (2 nt).

typedef __bf16 bf16x8 __attribute__((ext_vector_type(8)));
typedef float f32x4 __attribute__((ext_vector_type(4)));

#define TROWS 128

__device__ __forceinline__ unsigned short f2bf(float f) {
    union { float f; unsigned int u; } v; v.f = f;
    unsigned int u = v.u;
    return (unsigned short)((u + 0x7FFFu + ((u >> 16) & 1u)) >> 16);  // RNE
}
__device__ __forceinline__ ushort4 cvt4(float4 v) {
    ushort4 b;
    b.x = f2bf(v.x); b.y = f2bf(v.y); b.z = f2bf(v.z); b.w = f2bf(v.w);
    return b;
}
__device__ __forceinline__ bf16x8 pack8(float4 a, float4 b) {
    union { __hip_bfloat162 h[4]; bf16x8 v; } u;
    u.h[0] = __float22bfloat162_rn(float2{a.x, a.y});
    u.h[1] = __float22bfloat162_rn(float2{a.z, a.w});
    u.h[2] = __float22bfloat162_rn(float2{b.x, b.y});
    u.h[3] = __float22bfloat162_rn(float2{b.z, b.w});
    return u.v;
}

// ---- prep: (a) weights f32 -> bf16 [27][cout][cin]; (b) per-(offset,tile) range starts ----
__global__ __launch_bounds__(256) void sp3d_prep(
    const float* __restrict__ w, const int* __restrict__ nei,
    const int* __restrict__ sizes, unsigned short* __restrict__ wbf,
    int* __restrict__ starts, int P, int T, int wblocks)
{
    const int b = blockIdx.x;
    if (b < wblocks) {
        int id = b * 256 + threadIdx.x;            // one float4 per thread
        if (id < 27 * 64 * 16) {
            int k4 = id & 15, n = (id >> 4) & 63, tap = id >> 10;
            float4 v = *(const float4*)&w[n * 1728 + tap * 64 + k4 * 4];
            *(ushort4*)&wbf[(tap * 64 + n) * 64 + k4 * 4] = cvt4(v);
        }
    } else {
        int id = (b - wblocks) * 256 + threadIdx.x;
        if (id < 26 * (T + 1)) {
            int t = id % (T + 1), o = id / (T + 1);
            int target = t * TROWS;
            int lo = 0, hi = sizes[o];
            while (lo < hi) {                       // lower_bound on sorted out_idx
                int mid = (lo + hi) >> 1;
                if (nei[(o * P + mid) * 2] < target) lo = mid + 1; else hi = mid;
            }
            starts[o * (T + 1) + t] = lo;
        }
    }
}

// ---- main: one block per 128-row tile ----
__global__ __launch_bounds__(256, 3) void sp3d_main(
    const float* __restrict__ sp, const float* __restrict__ bias,
    const int* __restrict__ nei, const unsigned short* __restrict__ wbf,
    const int* __restrict__ starts, float* __restrict__ out,
    int N, int P, int T)
{
    __shared__ int tbl[27 * TROWS];   // tbl[tap][m] = in_row or -1
    __shared__ int sOff[27];
    __shared__ int sLo[26];

    const int t = threadIdx.x;
    const int w = t >> 6, lane = t & 63, ml = lane & 15, quad = lane >> 4;
    const int wrow = w >> 1, ch = w & 1;          // row-half, cout-half
    const int bid = blockIdx.x, row0 = bid * TROWS;
    const __bf16* Wg = (const __bf16*)wbf;

    // ---- build tbl (2 barriers total) ----
    for (int i = t; i < 27 * TROWS; i += 256) tbl[i] = -1;
    if (t < TROWS) { int r = row0 + t; tbl[13 * TROWS + t] = (r < N) ? r : -1; }
    if (t < 64) {  // wave 0: load 26 (lo,hi) ranges, exclusive scan of counts
        int o = t, lo = 0, cnt = 0;
        if (o < 26) {
            lo = starts[o * (T + 1) + bid];
            cnt = starts[o * (T + 1) + bid + 1] - lo;
            sLo[o] = lo;
        }
        int x = cnt;
        #pragma unroll
        for (int d = 1; d < 32; d <<= 1) {
            int y = __shfl_up(x, d);
            if (t >= d) x += y;
        }
        if (o < 26) sOff[o] = x - cnt;
        if (o == 25) sOff[26] = x;
    }
    __syncthreads();
    const int total = sOff[26];
    for (int s = t; s < total; s += 256) {
        int lo = 0, hi = 26;  // find o: sOff[o] <= s < sOff[o+1]
        while (hi - lo > 1) { int m = (lo + hi) >> 1; if (sOff[m] <= s) lo = m; else hi = m; }
        int o = lo;
        int2 e = *(const int2*)&nei[((long)o * P + sLo[o] + (s - sOff[o])) * 2];
        int tap = o + (o >= 13 ? 1 : 0);          // offsets enumeration skips center tap 13
        tbl[tap * TROWS + (e.x - row0)] = e.y;
    }
    __syncthreads();
    // ---- no more barriers below ----

    f32x4 acc[4][2];
    #pragma unroll
    for (int mt = 0; mt < 4; ++mt)
        #pragma unroll
        for (int nt = 0; nt < 2; ++nt) acc[mt][nt] = f32x4{0.f, 0.f, 0.f, 0.f};

    bf16x8 A0[4][2], A1[4][2], B0[2][2], B1[2][2];
    bool ac0[4], ac1[4];

    auto load_stage = [&](int tap, bf16x8 (&A)[4][2], bf16x8 (&B)[2][2], bool (&ac)[4]) {
        #pragma unroll
        for (int nt = 0; nt < 2; ++nt) {          // B: L2-hot, tap-static addresses
            const __bf16* bp = Wg + ((tap * 64 + ch * 32 + nt * 16 + ml) * 64 + quad * 8);
            B[nt][0] = *(const bf16x8*)bp;
            B[nt][1] = *(const bf16x8*)(bp + 32);
        }
        #pragma unroll
        for (int mt = 0; mt < 4; ++mt) {          // A: gather via tbl
            int idx = tbl[tap * TROWS + wrow * 64 + mt * 16 + ml];
            ac[mt] = __any(idx >= 0);
            float4 f0{0,0,0,0}, f1{0,0,0,0}, f2{0,0,0,0}, f3{0,0,0,0};
            if (idx >= 0) {
                const float* rp = sp + (long)idx * 64 + quad * 8;
                f0 = *(const float4*)rp;        f1 = *(const float4*)(rp + 4);
                f2 = *(const float4*)(rp + 32); f3 = *(const float4*)(rp + 36);
            }
            A[mt][0] = pack8(f0, f1);
            A[mt][1] = pack8(f2, f3);
        }
    };
    auto mfma_stage = [&](bf16x8 (&A)[4][2], bf16x8 (&B)[2][2], bool (&ac)[4]) {
        #pragma unroll
        for (int mt = 0; mt < 4; ++mt) {
            if (ac[mt]) {
                #pragma unroll
                for (int nt = 0; nt < 2; ++nt) {
                    acc[mt][nt] = __builtin_amdgcn_mfma_f32_16x16x32_bf16(A[mt][0], B[nt][0], acc[mt][nt], 0, 0, 0);
                    acc[mt][nt] = __builtin_amdgcn_mfma_f32_16x16x32_bf16(A[mt][1], B[nt][1], acc[mt][nt], 0, 0, 0);
                }
            }
        }
    };

    load_stage(0, A0, B0, ac0);
    for (int tap = 0; tap < 27; tap += 2) {
        if (tap + 1 < 27) load_stage(tap + 1, A1, B1, ac1);   // prefetch odd
        mfma_stage(A0, B0, ac0);                              // compute even
        if (tap + 1 < 27) {
            if (tap + 2 < 27) load_stage(tap + 2, A0, B0, ac0);  // prefetch even
            mfma_stage(A1, B1, ac1);                             // compute odd
        }
    }

    // ---- epilogue: acc + bias -> out (C layout: col = nt*16+ml, row = quad*4+rg) ----
    float bv[2];
    #pragma unroll
    for (int nt = 0; nt < 2; ++nt) bv[nt] = bias[ch * 32 + nt * 16 + ml];
    #pragma unroll
    for (int mt = 0; mt < 4; ++mt)
        #pragma unroll
        for (int rg = 0; rg < 4; ++rg) {
            long row = row0 + wrow * 64 + mt * 16 + quad * 4 + rg;
            if (row < N) {
                #pragma unroll
                for (int nt = 0; nt < 2; ++nt)
                    out[row * 64 + ch * 32 + nt * 16 + ml] = acc[mt][nt][rg] + bv[nt];
            }
        }
}

extern "C" void kernel_launch(void* const* d_in, const int* in_sizes, int n_in,
                              void* d_out, int out_size, void* d_ws, size_t ws_size,
                              hipStream_t stream) {
    const float* sp    = (const float*)d_in[0];
    const float* w     = (const float*)d_in[1];
    const float* bias  = (const float*)d_in[2];
    const int*   nei   = (const int*)d_in[3];
    const int*   sizes = (const int*)d_in[4];
    float* out = (float*)d_out;

    const int N = in_sizes[0] / 64;
    const int P = in_sizes[3] / 52;            // [26][P][2]
    const int T = (N + TROWS - 1) / TROWS;

    unsigned short* wbf = (unsigned short*)d_ws;
    int* starts = (int*)((char*)d_ws + 27 * 64 * 64 * 2);  // after 221184B of weights

    const int wblocks = (27 * 64 * 16 + 255) / 256;        // 108
    const int sblocks = (26 * (T + 1) + 255) / 256;
    sp3d_prep<<<wblocks + sblocks, 256, 0, stream>>>(w, nei, sizes, wbf, starts, P, T, wblocks);
    sp3d_main<<<T, 256, 0, stream>>>(sp, bias, nei, wbf, starts, out, N, P, T);
}

// Round 6
// 177.521 us; speedup vs baseline: 1.0186x; 1.0186x over previous
//
#include <hip/hip_runtime.h>
#include <hip/hip_bf16.h>

// SparseConv3D v6: one-wave blocks = many independent latency chains.
// Each 64-thread block owns a 64-row x 32-cout tile: builds tbl[tap][m] = in_row
// or -1 (row-aligned im2col), then 27 taps of register-accumulated MFMA with
// A gathered per-lane from global and B read from L2-hot bf16 weights.
// 3126 blocks -> ~12 independent wave-chains/CU (vs 4 in v4); __syncthreads in a
// 1-wave block is ~free, so no barrier-drain serialization. Whole-tap skip when
// the tile has no valid rows for that tap.

typedef __bf16 bf16x8 __attribute__((ext_vector_type(8)));
typedef float f32x4 __attribute__((ext_vector_type(4)));

#define TROWS 64

__device__ __forceinline__ unsigned short f2bf(float f) {
    union { float f; unsigned int u; } v; v.f = f;
    unsigned int u = v.u;
    return (unsigned short)((u + 0x7FFFu + ((u >> 16) & 1u)) >> 16);  // RNE
}
__device__ __forceinline__ ushort4 cvt4(float4 v) {
    ushort4 b;
    b.x = f2bf(v.x); b.y = f2bf(v.y); b.z = f2bf(v.z); b.w = f2bf(v.w);
    return b;
}
__device__ __forceinline__ bf16x8 pack8(float4 a, float4 b) {
    union { __hip_bfloat162 h[4]; bf16x8 v; } u;
    u.h[0] = __float22bfloat162_rn(float2{a.x, a.y});
    u.h[1] = __float22bfloat162_rn(float2{a.z, a.w});
    u.h[2] = __float22bfloat162_rn(float2{b.x, b.y});
    u.h[3] = __float22bfloat162_rn(float2{b.z, b.w});
    return u.v;
}

// ---- prep: (a) weights f32 -> bf16 [27][cout][cin]; (b) per-(offset,tile) range starts ----
__global__ __launch_bounds__(256) void sp3d_prep(
    const float* __restrict__ w, const int* __restrict__ nei,
    const int* __restrict__ sizes, unsigned short* __restrict__ wbf,
    int* __restrict__ starts, int P, int T, int wblocks)
{
    const int b = blockIdx.x;
    if (b < wblocks) {
        int id = b * 256 + threadIdx.x;            // one float4 per thread
        if (id < 27 * 64 * 16) {
            int k4 = id & 15, n = (id >> 4) & 63, tap = id >> 10;
            float4 v = *(const float4*)&w[n * 1728 + tap * 64 + k4 * 4];
            *(ushort4*)&wbf[(tap * 64 + n) * 64 + k4 * 4] = cvt4(v);
        }
    } else {
        int id = (b - wblocks) * 256 + threadIdx.x;
        if (id < 26 * (T + 1)) {
            int t = id % (T + 1), o = id / (T + 1);
            int target = t * TROWS;
            int lo = 0, hi = sizes[o];
            while (lo < hi) {                       // lower_bound on sorted out_idx
                int mid = (lo + hi) >> 1;
                if (nei[(o * P + mid) * 2] < target) lo = mid + 1; else hi = mid;
            }
            starts[o * (T + 1) + t] = lo;
        }
    }
}

// ---- main: one WAVE per block; blockIdx.x = 64-row tile, blockIdx.y = cout half ----
__global__ __launch_bounds__(64, 4) void sp3d_main(
    const float* __restrict__ sp, const float* __restrict__ bias,
    const int* __restrict__ nei, const unsigned short* __restrict__ wbf,
    const int* __restrict__ starts, float* __restrict__ out,
    int N, int P, int T)
{
    __shared__ int tbl[27 * TROWS];   // tbl[tap][m] = in_row or -1
    __shared__ int sOff[27];
    __shared__ int sLo[26];

    const int lane = threadIdx.x;                 // 0..63
    const int ml = lane & 15, quad = lane >> 4;
    const int bid = blockIdx.x, row0 = bid * TROWS;
    const int ch = blockIdx.y;                    // cout half (0: couts 0-31, 1: 32-63)
    const __bf16* Wg = (const __bf16*)wbf;

    // ---- build tbl (barriers are ~free: single wave) ----
    #pragma unroll
    for (int i = 0; i < 27; ++i) tbl[i * TROWS + lane] = -1;
    { int r = row0 + lane; if (r < N) tbl[13 * TROWS + lane] = r; }
    {
        int o = lane, lo = 0, cnt = 0;
        if (o < 26) {
            lo = starts[o * (T + 1) + bid];
            cnt = starts[o * (T + 1) + bid + 1] - lo;
            sLo[o] = lo;
        }
        int x = cnt;
        #pragma unroll
        for (int d = 1; d < 32; d <<= 1) {
            int y = __shfl_up(x, d);
            if (lane >= d) x += y;
        }
        if (o < 26) sOff[o] = x - cnt;
        if (o == 25) sOff[26] = x;
    }
    __syncthreads();
    const int total = sOff[26];
    for (int s = lane; s < total; s += 64) {
        int lo = 0, hi = 26;  // find o: sOff[o] <= s < sOff[o+1]
        while (hi - lo > 1) { int m = (lo + hi) >> 1; if (sOff[m] <= s) lo = m; else hi = m; }
        int o = lo;
        int2 e = *(const int2*)&nei[((long)o * P + sLo[o] + (s - sOff[o])) * 2];
        int tap = o + (o >= 13 ? 1 : 0);          // offsets enumeration skips center tap 13
        tbl[tap * TROWS + (e.x - row0)] = e.y;
    }
    __syncthreads();

    // ---- tap loop: simple, max per-tap ILP; TLP (12 chains/CU) hides latency ----
    f32x4 acc[4][2];   // [mt][nt] : 64 rows x 32 couts
    #pragma unroll
    for (int mt = 0; mt < 4; ++mt)
        #pragma unroll
        for (int nt = 0; nt < 2; ++nt) acc[mt][nt] = f32x4{0.f, 0.f, 0.f, 0.f};

    for (int tap = 0; tap < 27; ++tap) {
        int idx[4];
        bool act[4];
        #pragma unroll
        for (int mt = 0; mt < 4; ++mt) {
            idx[mt] = tbl[tap * TROWS + mt * 16 + ml];   // 4-lane broadcast per addr
            act[mt] = __any(idx[mt] >= 0);
        }
        if (!(act[0] | act[1] | act[2] | act[3])) continue;  // empty tap (~5%)

        // B frags: L2-hot, unconditional
        bf16x8 B[2][2];
        #pragma unroll
        for (int nt = 0; nt < 2; ++nt) {
            const __bf16* bp = Wg + ((tap * 64 + ch * 32 + nt * 16 + ml) * 64 + quad * 8);
            B[nt][0] = *(const bf16x8*)bp;
            B[nt][1] = *(const bf16x8*)(bp + 32);
        }
        // A frags: branchless clamped gather + post-mask (keeps loads hoistable)
        bf16x8 A[4][2];
        #pragma unroll
        for (int mt = 0; mt < 4; ++mt) {
            long r = (idx[mt] >= 0) ? idx[mt] : 0;
            const float* rp = sp + r * 64 + quad * 8;
            float4 f0 = *(const float4*)rp;
            float4 f1 = *(const float4*)(rp + 4);
            float4 f2 = *(const float4*)(rp + 32);
            float4 f3 = *(const float4*)(rp + 36);
            A[mt][0] = pack8(f0, f1);
            A[mt][1] = pack8(f2, f3);
            if (idx[mt] < 0) {                       // v_cndmask, no extra loads
                A[mt][0] = bf16x8{0, 0, 0, 0, 0, 0, 0, 0};
                A[mt][1] = bf16x8{0, 0, 0, 0, 0, 0, 0, 0};
            }
        }
        #pragma unroll
        for (int mt = 0; mt < 4; ++mt) {
            if (act[mt]) {
                #pragma unroll
                for (int nt = 0; nt < 2; ++nt) {
                    acc[mt][nt] = __builtin_amdgcn_mfma_f32_16x16x32_bf16(A[mt][0], B[nt][0], acc[mt][nt], 0, 0, 0);
                    acc[mt][nt] = __builtin_amdgcn_mfma_f32_16x16x32_bf16(A[mt][1], B[nt][1], acc[mt][nt], 0, 0, 0);
                }
            }
        }
    }

    // ---- epilogue: acc + bias -> out (C layout: col = nt*16+ml, row = quad*4+rg) ----
    float bv[2];
    #pragma unroll
    for (int nt = 0; nt < 2; ++nt) bv[nt] = bias[ch * 32 + nt * 16 + ml];
    #pragma unroll
    for (int mt = 0; mt < 4; ++mt)
        #pragma unroll
        for (int rg = 0; rg < 4; ++rg) {
            long row = row0 + mt * 16 + quad * 4 + rg;
            if (row < N) {
                #pragma unroll
                for (int nt = 0; nt < 2; ++nt)
                    out[row * 64 + ch * 32 + nt * 16 + ml] = acc[mt][nt][rg] + bv[nt];
            }
        }
}

extern "C" void kernel_launch(void* const* d_in, const int* in_sizes, int n_in,
                              void* d_out, int out_size, void* d_ws, size_t ws_size,
                              hipStream_t stream) {
    const float* sp    = (const float*)d_in[0];
    const float* w     = (const float*)d_in[1];
    const float* bias  = (const float*)d_in[2];
    const int*   nei   = (const int*)d_in[3];
    const int*   sizes = (const int*)d_in[4];
    float* out = (float*)d_out;

    const int N = in_sizes[0] / 64;
    const int P = in_sizes[3] / 52;            // [26][P][2]
    const int T = (N + TROWS - 1) / TROWS;

    unsigned short* wbf = (unsigned short*)d_ws;
    int* starts = (int*)((char*)d_ws + 27 * 64 * 64 * 2);  // after 221184B of weights

    const int wblocks = (27 * 64 * 16 + 255) / 256;        // 108
    const int sblocks = (26 * (T + 1) + 255) / 256;
    sp3d_prep<<<wblocks + sblocks, 256, 0, stream>>>(w, nei, sizes, wbf, starts, P, T, wblocks);
    dim3 g(T, 2);
    sp3d_main<<<g, 64, 0, stream>>>(sp, bias, nei, wbf, starts, out, N, P, T);
}